// Round 1
// baseline (214.711 us; speedup 1.0000x reference)
//
#include <hip/hip_runtime.h>

#define HDIM   256
#define HHALF  128
#define NTYPE  100
#define LS     36      // LDS k-major row stride in floats (padded, 16B-aligned: 36*4=144)

__device__ __forceinline__ float silu_f(float x) {
    return x / (1.0f + __expf(-x));
}

// One block = 32 crystals. Computes h_b = MLP(t_emb_b), then all three heads.
// h is kept TRANSPOSED (k-major) in LDS so the per-k fragment read is a single
// wave-uniform ds_read_b128 (broadcast, conflict-free).
__global__ __launch_bounds__(256) void crystal_kernel(
    const int* __restrict__ batch, int N,
    const float* __restrict__ t_emb, int B,
    const float* __restrict__ w1a, const float* __restrict__ b1a,
    const float* __restrict__ w2a, const float* __restrict__ b2a,
    const float* __restrict__ wc1, const float* __restrict__ bc1,
    const float* __restrict__ wc2, const float* __restrict__ bc2,
    const float* __restrict__ wl1, const float* __restrict__ bl1,
    const float* __restrict__ wl2, const float* __restrict__ bl2,
    const float* __restrict__ wt,  const float* __restrict__ bt,
    float* __restrict__ coord_b,   // [B,3]  ws
    float* __restrict__ logits_b,  // [B,100] ws
    float* __restrict__ cell_out)  // d_out + N*3, [B,6]
{
    __shared__ float bufA[HDIM * LS];   // 36 KB: hT (k-major [256][36])
    __shared__ float bufB[HDIM * LS];   // 36 KB: h1T, later gcT/glT
    __shared__ int   lb_s[33];
    __shared__ float cnt_s[32];

    const int tid = threadIdx.x;
    const int R0  = blockIdx.x * 32;

    // per-crystal atom counts via binary search on sorted batch (no atomics)
    if (tid <= 32) {
        int v = R0 + tid;
        int lo = 0, hi = N;
        while (lo < hi) { int mid = (lo + hi) >> 1; if (batch[mid] < v) lo = mid + 1; else hi = mid; }
        lb_s[tid] = lo;
    }

    // stage t_emb rows R0..R0+31 transposed into bufA: bufA[k*LS + r] = t_emb[(R0+r)*H + k]
    for (int idx = tid; idx < 32 * HDIM; idx += 256) {
        int r = idx >> 8;     // / 256
        int k = idx & 255;
        bufA[k * LS + r] = t_emb[(size_t)(R0 + r) * HDIM + k];
    }
    __syncthreads();
    if (tid < 32) cnt_s[tid] = (float)(lb_s[tid + 1] - lb_s[tid]);

    const int cg = tid & 31;      // col-group: 8 cols
    const int rg = tid >> 5;      // row-group: 4 rows
    const int j0 = cg * 8;
    const int r0 = rg * 4;

    // ---------------- layer 1: h1 = silu(h0 @ w1a + b1a) ----------------
    {
        float4 acc[8];
        #pragma unroll
        for (int c = 0; c < 8; ++c) acc[c] = make_float4(0.f, 0.f, 0.f, 0.f);
        #pragma unroll 2
        for (int k = 0; k < HDIM; ++k) {
            float4 hv = *(const float4*)&bufA[k * LS + r0];
            const float* wr = w1a + (size_t)k * HDIM + j0;
            float4 wa = *(const float4*)(wr);
            float4 wb = *(const float4*)(wr + 4);
            float wv[8] = {wa.x, wa.y, wa.z, wa.w, wb.x, wb.y, wb.z, wb.w};
            #pragma unroll
            for (int c = 0; c < 8; ++c) {
                acc[c].x += hv.x * wv[c]; acc[c].y += hv.y * wv[c];
                acc[c].z += hv.z * wv[c]; acc[c].w += hv.w * wv[c];
            }
        }
        #pragma unroll
        for (int c = 0; c < 8; ++c) {
            float b = b1a[j0 + c];
            float4 v;
            v.x = silu_f(acc[c].x + b); v.y = silu_f(acc[c].y + b);
            v.z = silu_f(acc[c].z + b); v.w = silu_f(acc[c].w + b);
            *(float4*)&bufB[(j0 + c) * LS + r0] = v;
        }
    }
    __syncthreads();

    // ---------------- layer 2: h = h1 @ w2a + b2a (no act) ----------------
    {
        float4 acc[8];
        #pragma unroll
        for (int c = 0; c < 8; ++c) acc[c] = make_float4(0.f, 0.f, 0.f, 0.f);
        #pragma unroll 2
        for (int k = 0; k < HDIM; ++k) {
            float4 hv = *(const float4*)&bufB[k * LS + r0];
            const float* wr = w2a + (size_t)k * HDIM + j0;
            float4 wa = *(const float4*)(wr);
            float4 wb = *(const float4*)(wr + 4);
            float wv[8] = {wa.x, wa.y, wa.z, wa.w, wb.x, wb.y, wb.z, wb.w};
            #pragma unroll
            for (int c = 0; c < 8; ++c) {
                acc[c].x += hv.x * wv[c]; acc[c].y += hv.y * wv[c];
                acc[c].z += hv.z * wv[c]; acc[c].w += hv.w * wv[c];
            }
        }
        #pragma unroll
        for (int c = 0; c < 8; ++c) {
            float b = b2a[j0 + c];
            float4 v;
            v.x = acc[c].x + b; v.y = acc[c].y + b;
            v.z = acc[c].z + b; v.w = acc[c].w + b;
            *(float4*)&bufA[(j0 + c) * LS + r0] = v;   // h (k-major) -> bufA
        }
    }
    __syncthreads();

    // ------------- head hidden layers: coord (waves 0-1), cell (waves 2-3) -------------
    {
        const int t    = tid & 127;
        const int hcg  = t & 15;          // 16 col-groups * 8 cols = 128
        const int hrg  = t >> 4;          // 8 row-groups * 4 rows  = 32
        const int hj0  = hcg * 8;
        const int hr0  = hrg * 4;
        const bool is_cell = (tid >= 128);
        const float* W  = is_cell ? wl1 : wc1;
        const float* bb = is_cell ? bl1 : bc1;

        float4 acc[8];
        #pragma unroll
        for (int c = 0; c < 8; ++c) acc[c] = make_float4(0.f, 0.f, 0.f, 0.f);
        #pragma unroll 2
        for (int k = 0; k < HDIM; ++k) {
            float4 hv = *(const float4*)&bufA[k * LS + hr0];
            const float* wr = W + (size_t)k * HHALF + hj0;
            float4 wa = *(const float4*)(wr);
            float4 wb = *(const float4*)(wr + 4);
            float wv[8] = {wa.x, wa.y, wa.z, wa.w, wb.x, wb.y, wb.z, wb.w};
            #pragma unroll
            for (int c = 0; c < 8; ++c) {
                acc[c].x += hv.x * wv[c]; acc[c].y += hv.y * wv[c];
                acc[c].z += hv.z * wv[c]; acc[c].w += hv.w * wv[c];
            }
        }
        // cell head: segment_sum == count * h, and scale commutes through the dot
        float4 cv = make_float4(1.f, 1.f, 1.f, 1.f);
        if (is_cell) cv = *(const float4*)&cnt_s[hr0];
        float* dst = bufB + (is_cell ? HHALF * LS : 0);
        #pragma unroll
        for (int c = 0; c < 8; ++c) {
            float b = bb[hj0 + c];
            float4 v;
            v.x = silu_f(acc[c].x * cv.x + b); v.y = silu_f(acc[c].y * cv.y + b);
            v.z = silu_f(acc[c].z * cv.z + b); v.w = silu_f(acc[c].w * cv.w + b);
            *(float4*)&dst[(hj0 + c) * LS + hr0] = v;
        }
    }
    __syncthreads();

    // ---------------- atom-type logits: h @ wt + bt  (32 x 100, k=256) ----------------
    {
        const int lcg = tid & 31;     // 25 active col-groups * 4 cols = 100
        const int lrg = tid >> 5;
        const int lj0 = lcg * 4;
        const int lr0 = lrg * 4;
        if (lcg < 25) {
            float4 a0 = make_float4(0,0,0,0), a1 = a0, a2 = a0, a3 = a0;
            #pragma unroll 2
            for (int k = 0; k < HDIM; ++k) {
                float4 hv = *(const float4*)&bufA[k * LS + lr0];
                float4 w4 = *(const float4*)&wt[(size_t)k * NTYPE + lj0];
                a0.x += hv.x * w4.x; a0.y += hv.y * w4.x; a0.z += hv.z * w4.x; a0.w += hv.w * w4.x;
                a1.x += hv.x * w4.y; a1.y += hv.y * w4.y; a1.z += hv.z * w4.y; a1.w += hv.w * w4.y;
                a2.x += hv.x * w4.z; a2.y += hv.y * w4.z; a2.z += hv.z * w4.z; a2.w += hv.w * w4.z;
                a3.x += hv.x * w4.w; a3.y += hv.y * w4.w; a3.z += hv.z * w4.w; a3.w += hv.w * w4.w;
            }
            float4 b4 = *(const float4*)&bt[lj0];
            float4 r;
            r = make_float4(a0.x + b4.x, a1.x + b4.y, a2.x + b4.z, a3.x + b4.w);
            *(float4*)&logits_b[(size_t)(R0 + lr0 + 0) * NTYPE + lj0] = r;
            r = make_float4(a0.y + b4.x, a1.y + b4.y, a2.y + b4.z, a3.y + b4.w);
            *(float4*)&logits_b[(size_t)(R0 + lr0 + 1) * NTYPE + lj0] = r;
            r = make_float4(a0.z + b4.x, a1.z + b4.y, a2.z + b4.z, a3.z + b4.w);
            *(float4*)&logits_b[(size_t)(R0 + lr0 + 2) * NTYPE + lj0] = r;
            r = make_float4(a0.w + b4.x, a1.w + b4.y, a2.w + b4.z, a3.w + b4.w);
            *(float4*)&logits_b[(size_t)(R0 + lr0 + 3) * NTYPE + lj0] = r;
        }
    }

    // ---------------- tiny head outputs: coord [32x3], cell [32x6] ----------------
    for (int t = tid; t < 96 + 192; t += 256) {
        if (t < 96) {
            int r = t / 3, c = t - 3 * r;
            float a = bc2[c];
            for (int k = 0; k < HHALF; ++k)
                a += bufB[k * LS + r] * wc2[k * 3 + c];
            coord_b[(size_t)(R0 + r) * 3 + c] = a;
        } else {
            int t2 = t - 96;
            int r = t2 / 6, c = t2 - 6 * r;
            float a = bl2[c];
            for (int k = 0; k < HHALF; ++k)
                a += bufB[HHALF * LS + k * LS + r] * wl2[k * 6 + c];
            cell_out[(size_t)(R0 + r) * 6 + c] = a;
        }
    }
}

// Gather per-crystal tables out to per-atom outputs. Pure HBM-write-bound.
__global__ __launch_bounds__(256) void scatter_kernel(
    const int* __restrict__ batch,
    const float*  __restrict__ coord_b,
    const float4* __restrict__ logits_b4,   // [B][25] float4
    float*  __restrict__ out_coord,         // [N*3]
    float4* __restrict__ out_logits4,       // [N*25] float4
    int N)
{
    const int stride = gridDim.x * blockDim.x;
    const int g0 = blockIdx.x * blockDim.x + threadIdx.x;

    const int tot_c = N * 3;
    for (int g = g0; g < tot_c; g += stride) {
        unsigned ug = (unsigned)g;
        unsigned i = ug / 3u;
        unsigned c = ug - i * 3u;
        out_coord[g] = coord_b[3u * (unsigned)batch[i] + c];
    }

    const int tot_l = N * 25;
    for (int g = g0; g < tot_l; g += stride) {
        unsigned ug = (unsigned)g;
        unsigned i = ug / 25u;
        unsigned q = ug - i * 25u;
        out_logits4[g] = logits_b4[25u * (unsigned)batch[i] + q];
    }
}

extern "C" void kernel_launch(void* const* d_in, const int* in_sizes, int n_in,
                              void* d_out, int out_size, void* d_ws, size_t ws_size,
                              hipStream_t stream)
{
    // setup_inputs order: pos, batch, cell, t_embedding, w1a,b1a,w2a,b2a,
    //                     wc1,bc1,wc2,bc2, wl1,bl1,wl2,bl2, wt,bt
    const int*   batch = (const int*)d_in[1];
    const float* t_emb = (const float*)d_in[3];
    const float* w1a = (const float*)d_in[4];
    const float* b1a = (const float*)d_in[5];
    const float* w2a = (const float*)d_in[6];
    const float* b2a = (const float*)d_in[7];
    const float* wc1 = (const float*)d_in[8];
    const float* bc1 = (const float*)d_in[9];
    const float* wc2 = (const float*)d_in[10];
    const float* bc2 = (const float*)d_in[11];
    const float* wl1 = (const float*)d_in[12];
    const float* bl1 = (const float*)d_in[13];
    const float* wl2 = (const float*)d_in[14];
    const float* bl2 = (const float*)d_in[15];
    const float* wt  = (const float*)d_in[16];
    const float* bt  = (const float*)d_in[17];

    const int N = in_sizes[1];        // 500000
    const int B = in_sizes[2] / 9;    // 4096

    float* out        = (float*)d_out;
    float* out_coord  = out;                                   // [N,3]
    float* cell_out   = out + (size_t)N * 3;                   // [B,6]
    float* out_logits = out + (size_t)N * 3 + (size_t)B * 6;   // [N,100]

    float* logits_b = (float*)d_ws;                            // B*100 floats
    float* coord_b  = logits_b + (size_t)B * NTYPE;            // B*3 floats

    crystal_kernel<<<B / 32, 256, 0, stream>>>(
        batch, N, t_emb, B,
        w1a, b1a, w2a, b2a,
        wc1, bc1, wc2, bc2,
        wl1, bl1, wl2, bl2,
        wt, bt,
        coord_b, logits_b, cell_out);

    scatter_kernel<<<2048, 256, 0, stream>>>(
        batch, coord_b, (const float4*)logits_b,
        out_coord, (float4*)out_logits, N);
}

// Round 2
// 153.791 us; speedup vs baseline: 1.3961x; 1.3961x over previous
//
#include <hip/hip_runtime.h>

#define HDIM   256
#define HHALF  128
#define NTYPE  100
#define RPB    8       // crystals (rows) per block
#define S      260     // LDS row stride in floats (256 + 4 pad)

__device__ __forceinline__ float silu_f(float x) {
    return x / (1.0f + __expf(-x));
}

// GEMM row-tile: one thread computes 1 row x 8 cols, K=256.
// hrow points at an LDS row (reads are wave-broadcast). W is [256 x ldw]
// row-major in global (L2-resident). dst gets 8 contiguous floats.
template<bool ACT>
__device__ __forceinline__ void gemm8(const float* hrow, const float* __restrict__ W,
                                      int ldw, const float* __restrict__ bias,
                                      int j0, float scale, float* dst)
{
    float acc[8];
#pragma unroll
    for (int c = 0; c < 8; ++c) acc[c] = 0.f;

#pragma unroll 2
    for (int k = 0; k < HDIM; k += 4) {
        float4 hv = *(const float4*)(hrow + k);
        const float* w = W + (size_t)k * ldw + j0;
        float hk[4] = {hv.x, hv.y, hv.z, hv.w};
#pragma unroll
        for (int kk = 0; kk < 4; ++kk) {
            float4 wa = *(const float4*)(w + kk * ldw);
            float4 wb = *(const float4*)(w + kk * ldw + 4);
            float h1 = hk[kk];
            acc[0] += h1 * wa.x; acc[1] += h1 * wa.y;
            acc[2] += h1 * wa.z; acc[3] += h1 * wa.w;
            acc[4] += h1 * wb.x; acc[5] += h1 * wb.y;
            acc[6] += h1 * wb.z; acc[7] += h1 * wb.w;
        }
    }
    float4 ba = *(const float4*)(bias + j0);
    float4 bb = *(const float4*)(bias + j0 + 4);
    float bv[8] = {ba.x, ba.y, ba.z, ba.w, bb.x, bb.y, bb.z, bb.w};
    float r[8];
#pragma unroll
    for (int c = 0; c < 8; ++c) {
        float v = acc[c] * scale + bv[c];
        r[c] = ACT ? silu_f(v) : v;
    }
    *(float4*)(dst)     = make_float4(r[0], r[1], r[2], r[3]);
    *(float4*)(dst + 4) = make_float4(r[4], r[5], r[6], r[7]);
}

// One block = 8 crystals. h kept ROW-major in LDS; per-k reads broadcast.
__global__ __launch_bounds__(256) void crystal_kernel(
    const int* __restrict__ batch, int N,
    const float* __restrict__ t_emb,
    const float* __restrict__ w1a, const float* __restrict__ b1a,
    const float* __restrict__ w2a, const float* __restrict__ b2a,
    const float* __restrict__ wc1, const float* __restrict__ bc1,
    const float* __restrict__ wc2, const float* __restrict__ bc2,
    const float* __restrict__ wl1, const float* __restrict__ bl1,
    const float* __restrict__ wl2, const float* __restrict__ bl2,
    const float* __restrict__ wt,  const float* __restrict__ bt,
    float* __restrict__ coord_b,   // [B,3]  ws
    float* __restrict__ logits_b,  // [B,100] ws
    float* __restrict__ cell_out)  // d_out + N*3, [B,6]
{
    __shared__ float bufA[RPB * S];   // ~8.1 KB: h0, then h
    __shared__ float bufB[RPB * S];   // ~8.1 KB: h1, then gc(cols 0..127)/gl(128..255)
    __shared__ int   lb_s[RPB + 1];
    __shared__ float cnt_s[RPB];

    const int tid = threadIdx.x;
    const int R0  = blockIdx.x * RPB;

    // per-crystal atom counts via binary search on sorted batch
    if (tid <= RPB) {
        int v = R0 + tid;
        int lo = 0, hi = N;
        while (lo < hi) { int mid = (lo + hi) >> 1; if (batch[mid] < v) lo = mid + 1; else hi = mid; }
        lb_s[tid] = lo;
    }

    // stage t_emb rows R0..R0+7 row-major (coalesced float4)
    {
        const float4* src = (const float4*)(t_emb + (size_t)R0 * HDIM);
        for (int i = tid; i < RPB * 64; i += 256) {
            int r = i >> 6, kq = i & 63;
            *(float4*)&bufA[r * S + kq * 4] = src[r * 64 + kq];
        }
    }
    __syncthreads();
    if (tid < RPB) cnt_s[tid] = (float)(lb_s[tid + 1] - lb_s[tid]);

    const int cg = tid & 31;      // 32 col-groups x 8 cols = 256
    const int rg = tid >> 5;      // 8 rows
    const int j0 = cg * 8;

    // layer 1: h1 = silu(h0 @ w1a + b1a)    bufA -> bufB
    gemm8<true>(&bufA[rg * S], w1a, HDIM, b1a, j0, 1.f, &bufB[rg * S + j0]);
    __syncthreads();

    // layer 2: h = h1 @ w2a + b2a           bufB -> bufA
    gemm8<false>(&bufB[rg * S], w2a, HDIM, b2a, j0, 1.f, &bufA[rg * S + j0]);
    __syncthreads();

    // heads: coord hidden (tid<128) / cell hidden (tid>=128)   bufA -> bufB
    {
        const int t   = tid & 127;
        const int hcg = t & 15;        // 16 col-groups x 8 = 128 cols
        const int hrg = t >> 4;        // 8 rows
        const int hj0 = hcg * 8;
        const bool is_cell = (tid >= 128);
        const float* W  = is_cell ? wl1 : wc1;
        const float* bb = is_cell ? bl1 : bc1;
        // segment_sum == count * h; scale commutes through the dot product
        const float sc = is_cell ? cnt_s[hrg] : 1.f;
        float* dst = &bufB[hrg * S + (is_cell ? HHALF : 0) + hj0];
        gemm8<true>(&bufA[hrg * S], W, HHALF, bb, hj0, sc, dst);
    }
    __syncthreads();

    // logits (lanes lcg<25) + tiny head outputs (lanes lcg>=25), one phase
    {
        const int lcg = tid & 31;
        const int lrg = tid >> 5;      // 8 rows
        if (lcg < 25) {
            const int lj0 = lcg * 4;
            float a0 = 0.f, a1 = 0.f, a2 = 0.f, a3 = 0.f;
#pragma unroll 2
            for (int k = 0; k < HDIM; k += 4) {
                float4 hv = *(const float4*)&bufA[lrg * S + k];
                float hk[4] = {hv.x, hv.y, hv.z, hv.w};
#pragma unroll
                for (int kk = 0; kk < 4; ++kk) {
                    float4 w4 = *(const float4*)&wt[(size_t)(k + kk) * NTYPE + lj0];
                    a0 += hk[kk] * w4.x; a1 += hk[kk] * w4.y;
                    a2 += hk[kk] * w4.z; a3 += hk[kk] * w4.w;
                }
            }
            float4 b4 = *(const float4*)&bt[lj0];
            *(float4*)&logits_b[(size_t)(R0 + lrg) * NTYPE + lj0] =
                make_float4(a0 + b4.x, a1 + b4.y, a2 + b4.z, a3 + b4.w);
        } else {
            // 56 idle lanes cover 24 coord + 48 cell outputs
            int idx = lrg * 7 + (lcg - 25);
            for (int t = idx; t < 24 + 48; t += 56) {
                if (t < 24) {
                    int r = t / 3, c = t - 3 * r;
                    float a = 0.f;
#pragma unroll 4
                    for (int k = 0; k < HHALF; k += 4) {
                        float4 hv = *(const float4*)&bufB[r * S + k];
                        a += hv.x * wc2[(k + 0) * 3 + c] + hv.y * wc2[(k + 1) * 3 + c]
                           + hv.z * wc2[(k + 2) * 3 + c] + hv.w * wc2[(k + 3) * 3 + c];
                    }
                    coord_b[(size_t)(R0 + r) * 3 + c] = a + bc2[c];
                } else {
                    int t2 = t - 24;
                    int r = t2 / 6, c = t2 - 6 * r;
                    float a = 0.f;
#pragma unroll 4
                    for (int k = 0; k < HHALF; k += 4) {
                        float4 hv = *(const float4*)&bufB[r * S + HHALF + k];
                        a += hv.x * wl2[(k + 0) * 6 + c] + hv.y * wl2[(k + 1) * 6 + c]
                           + hv.z * wl2[(k + 2) * 6 + c] + hv.w * wl2[(k + 3) * 6 + c];
                    }
                    cell_out[(size_t)(R0 + r) * 6 + c] = a + bl2[c];
                }
            }
        }
    }
}

// Gather per-crystal tables out to per-atom outputs. HBM-write-bound (~206 MB).
__global__ __launch_bounds__(256) void scatter_kernel(
    const int* __restrict__ batch,
    const float*  __restrict__ coord_b,
    const float4* __restrict__ logits_b4,   // [B][25] float4
    float*  __restrict__ out_coord,         // [N*3]
    float4* __restrict__ out_logits4,       // [N*25] float4
    int N)
{
    const int stride = gridDim.x * blockDim.x;
    const int g0 = blockIdx.x * blockDim.x + threadIdx.x;

    const int tot_c = N * 3;
    for (int g = g0; g < tot_c; g += stride) {
        unsigned ug = (unsigned)g;
        unsigned i = ug / 3u;
        unsigned c = ug - i * 3u;
        out_coord[g] = coord_b[3u * (unsigned)batch[i] + c];
    }

    const int tot_l = N * 25;
    for (int g = g0; g < tot_l; g += stride) {
        unsigned ug = (unsigned)g;
        unsigned i = ug / 25u;
        unsigned q = ug - i * 25u;
        out_logits4[g] = logits_b4[25u * (unsigned)batch[i] + q];
    }
}

extern "C" void kernel_launch(void* const* d_in, const int* in_sizes, int n_in,
                              void* d_out, int out_size, void* d_ws, size_t ws_size,
                              hipStream_t stream)
{
    // setup_inputs order: pos, batch, cell, t_embedding, w1a,b1a,w2a,b2a,
    //                     wc1,bc1,wc2,bc2, wl1,bl1,wl2,bl2, wt,bt
    const int*   batch = (const int*)d_in[1];
    const float* t_emb = (const float*)d_in[3];
    const float* w1a = (const float*)d_in[4];
    const float* b1a = (const float*)d_in[5];
    const float* w2a = (const float*)d_in[6];
    const float* b2a = (const float*)d_in[7];
    const float* wc1 = (const float*)d_in[8];
    const float* bc1 = (const float*)d_in[9];
    const float* wc2 = (const float*)d_in[10];
    const float* bc2 = (const float*)d_in[11];
    const float* wl1 = (const float*)d_in[12];
    const float* bl1 = (const float*)d_in[13];
    const float* wl2 = (const float*)d_in[14];
    const float* bl2 = (const float*)d_in[15];
    const float* wt  = (const float*)d_in[16];
    const float* bt  = (const float*)d_in[17];

    const int N = in_sizes[1];        // 500000
    const int B = in_sizes[2] / 9;    // 4096

    float* out        = (float*)d_out;
    float* out_coord  = out;                                   // [N,3]
    float* cell_out   = out + (size_t)N * 3;                   // [B,6]
    float* out_logits = out + (size_t)N * 3 + (size_t)B * 6;   // [N,100]

    float* logits_b = (float*)d_ws;                            // B*100 floats
    float* coord_b  = logits_b + (size_t)B * NTYPE;            // B*3 floats

    crystal_kernel<<<B / RPB, 256, 0, stream>>>(
        batch, N, t_emb,
        w1a, b1a, w2a, b2a,
        wc1, bc1, wc2, bc2,
        wl1, bl1, wl2, bl2,
        wt, bt,
        coord_b, logits_b, cell_out);

    scatter_kernel<<<2048, 256, 0, stream>>>(
        batch, coord_b, (const float4*)logits_b,
        out_coord, (float4*)out_logits, N);
}